// Round 3
// baseline (526.605 us; speedup 1.0000x reference)
//
#include <hip/hip_runtime.h>

// ---------------------------------------------------------------------------
// Attention_49185965474367: B=4, N=1024, D=1024, H=16, DH=64, INNER=1024
// R3: attn rewritten barrier-free — K/V B-frags loaded straight from global
//     (layouts are frag-contiguous), 1 wave/block, rel register-prefetched.
//     GEMMs (global_load_lds m97-style) and transpose-casts unchanged.
// ---------------------------------------------------------------------------

#define NEGMAX 3.402823466e+38f

typedef short short8 __attribute__((ext_vector_type(8)));
typedef float f32x4 __attribute__((ext_vector_type(4)));

__device__ __forceinline__ unsigned short f2bf(float f) {
  unsigned int u = __float_as_uint(f);
  u += 0x7FFFu + ((u >> 16) & 1u);   // round-to-nearest-even
  return (unsigned short)(u >> 16);
}

// async global->LDS, 16B per lane. lds_base must be wave-uniform; HW scatters
// lane i to lds_base + i*16 (guide §5; padding-free layouts only).
__device__ __forceinline__ void stage16(const void* g, void* lds_base, int lane) {
#if __has_builtin(__builtin_amdgcn_global_load_lds)
  __builtin_amdgcn_global_load_lds(
      (const __attribute__((address_space(1))) unsigned int*)g,
      (__attribute__((address_space(3))) unsigned int*)lds_base, 16, 0, 0);
#else
  *(int4*)((char*)lds_base + lane * 16) = *(const int4*)g;
#endif
}

// ---------------- cast kernels ---------------------------------------------
__global__ void cast_x_k(const float* __restrict__ x, unsigned short* __restrict__ xb) {
  int i = (blockIdx.x * 256 + threadIdx.x) * 4;
  float4 v = *(const float4*)(x + i);
  ushort4 o;
  o.x = f2bf(v.x); o.y = f2bf(v.y); o.z = f2bf(v.z); o.w = f2bf(v.w);
  *(ushort4*)(xb + i) = o;
}

// dst[n][d] = src[d][n]  (src fp32 [1024 x ldsrc], dst bf16 rows of 1024)
__global__ __launch_bounds__(256) void tcast_k(const float* __restrict__ src, int ldsrc,
                                               unsigned short* __restrict__ dst) {
  __shared__ float T[64][65];
  const int n0 = blockIdx.x * 64, d0 = blockIdx.y * 64;
  const int tx = threadIdx.x & 63, ty = threadIdx.x >> 6;
#pragma unroll
  for (int k = 0; k < 16; ++k) {
    int dl = k * 4 + ty;
    T[dl][tx] = src[(size_t)(d0 + dl) * ldsrc + n0 + tx];
  }
  __syncthreads();
#pragma unroll
  for (int k = 0; k < 16; ++k) {
    int nl = k * 4 + ty;
    dst[(size_t)(n0 + nl) * 1024 + d0 + tx] = f2bf(T[tx][nl]);
  }
}

// ---------------- GEMM: C[M,N] = A[M,K] @ Bt[N,K]^T  (bf16 in, fp32 acc) ---
// 128x128 tile, BK=32, 256 threads (4 waves), global_load_lds staging (m97).
template <int MODE>
__global__ __launch_bounds__(256) void gemm_bt_k(
    const unsigned short* __restrict__ A, const unsigned short* __restrict__ Bt,
    unsigned short* __restrict__ qws, unsigned short* __restrict__ kws,
    unsigned short* __restrict__ vtws,
    const float* __restrict__ bias, float* __restrict__ Cout) {
  constexpr int K = 1024;
  constexpr int NKB = K / 32;
  __shared__ alignas(16) unsigned short As[128 * 32];
  __shared__ alignas(16) unsigned short Bs[128 * 32];
  const int tid = threadIdx.x;
  const int lane = tid & 63, w = tid >> 6;
  const int quad = lane >> 4, lanelo = lane & 15;
  const int tRow = blockIdx.y * 128, tCol = blockIdx.x * 128;
  const int wr = (w >> 1) * 64, wc = (w & 1) * 64;
  const char* AgB = (const char*)(A + (size_t)tRow * K);
  const char* BgB = (const char*)(Bt + (size_t)tCol * K);
  const int c0 = tid, c1 = tid + 256;
  const size_t a0off = (size_t)(c0 >> 2) * 2048 + (c0 & 3) * 16;
  const size_t a1off = (size_t)(c1 >> 2) * 2048 + (c1 & 3) * 16;
  char* ldsA0 = (char*)As + w * 1024;
  char* ldsA1 = (char*)As + 4096 + w * 1024;
  char* ldsB0 = (char*)Bs + w * 1024;
  char* ldsB1 = (char*)Bs + 4096 + w * 1024;

  f32x4 acc[4][4];
#pragma unroll
  for (int i = 0; i < 4; ++i)
#pragma unroll
    for (int j = 0; j < 4; ++j) acc[i][j] = (f32x4){0.f, 0.f, 0.f, 0.f};

  for (int kb = 0; kb < NKB; ++kb) {
    if (kb) __syncthreads();
    const size_t ko = (size_t)kb * 64;
    stage16(AgB + a0off + ko, ldsA0, lane);
    stage16(AgB + a1off + ko, ldsA1, lane);
    stage16(BgB + a0off + ko, ldsB0, lane);
    stage16(BgB + a1off + ko, ldsB1, lane);
    __syncthreads();   // drains vmcnt before any frag read

    short8 af[4], bf[4];
#pragma unroll
    for (int i = 0; i < 4; ++i)
      af[i] = *(const short8*)(As + (wr + i * 16 + lanelo) * 32 + quad * 8);
#pragma unroll
    for (int j = 0; j < 4; ++j)
      bf[j] = *(const short8*)(Bs + (wc + j * 16 + lanelo) * 32 + quad * 8);
#pragma unroll
    for (int i = 0; i < 4; ++i)
#pragma unroll
      for (int j = 0; j < 4; ++j)
        acc[i][j] = __builtin_amdgcn_mfma_f32_16x16x32_bf16(af[i], bf[j], acc[i][j], 0, 0, 0);
  }

  if (MODE == 0) {
#pragma unroll
    for (int i = 0; i < 4; ++i) {
      int row = tRow + wr + i * 16 + quad * 4;
      int b_ = row >> 10;
      int npos = row & 1023;
#pragma unroll
      for (int j = 0; j < 4; ++j) {
        int col = tCol + wc + j * 16 + lanelo;
        if (col < 2048) {
          unsigned short* dst = (col < 1024) ? qws : kws;
          int c = col & 1023;
          int hh = c >> 6, dh = c & 63;
          size_t base = ((size_t)(b_ * 16 + hh) * 1024 + npos) * 64 + dh;
#pragma unroll
          for (int r = 0; r < 4; ++r) dst[base + (size_t)r * 64] = f2bf(acc[i][j][r]);
        } else {
          int c = col - 2048;
          ushort4 pk;
          pk.x = f2bf(acc[i][j][0]);
          pk.y = f2bf(acc[i][j][1]);
          pk.z = f2bf(acc[i][j][2]);
          pk.w = f2bf(acc[i][j][3]);
          *(ushort4*)&vtws[((size_t)(b_ * 16 + (c >> 6)) * 64 + (c & 63)) * 1024 + npos] = pk;
        }
      }
    }
  } else {
#pragma unroll
    for (int i = 0; i < 4; ++i) {
      int row = tRow + wr + i * 16 + quad * 4;
#pragma unroll
      for (int j = 0; j < 4; ++j) {
        int col = tCol + wc + j * 16 + lanelo;
        float bv = bias[col];
#pragma unroll
        for (int r = 0; r < 4; ++r)
          Cout[(size_t)(row + r) * 1024 + col] = acc[i][j][r] + bv;
      }
    }
  }
}

// ---------------- flash attention, barrier-free, 1 wave/block --------------
// grid (64, 64): x = q-tile (16 rows), y = bh. 64 threads = 1 wave.
// q,k: bf16 [bh][n][64]; vt: bf16 [bh][dh][n]; rel fp32 [bh][n][n].
// K/V MFMA B-frags are contiguous short8 in global -> no shared staging,
// no __syncthreads anywhere. Pl is per-wave (same-wave dep only).
__global__ __launch_bounds__(64) void attn_k(
    const unsigned short* __restrict__ q_ws, const unsigned short* __restrict__ k_ws,
    const unsigned short* __restrict__ vt_ws, const float* __restrict__ rel,
    const int* __restrict__ qmask, const int* __restrict__ cmask,
    unsigned short* __restrict__ aout) {
  constexpr float SCALE = 0.125f;  // 64^-0.5
  __shared__ alignas(16) unsigned short Pl[16 * 72];  // 16 q-rows x 64 keys (+pad)

  const int lane = threadIdx.x;
  const int quad = lane >> 4, lanelo = lane & 15;
  const int bh = blockIdx.y, b_ = bh >> 4, h = bh & 15;
  const int qrow0 = blockIdx.x * 16;

  const unsigned short* qg = q_ws + ((size_t)bh * 1024 + qrow0) * 64;
  short8 qf0 = *(const short8*)(qg + lanelo * 64 + quad * 8);
  short8 qf1 = *(const short8*)(qg + lanelo * 64 + 32 + quad * 8);

  float qmv[4];
#pragma unroll
  for (int r = 0; r < 4; ++r)
    qmv[r] = (qmask[b_ * 1024 + qrow0 + quad * 4 + r] != 0) ? 1.f : 0.f;

  const unsigned short* kg = k_ws + (size_t)bh * 65536;   // [key][dh]
  const unsigned short* vg = vt_ws + (size_t)bh * 65536;  // [dh][key]
  const float* relg = rel + ((size_t)bh * 1024 + qrow0) * 1024;
  const int* cmg = cmask + b_ * 1024;

  f32x4 o[4];
#pragma unroll
  for (int g = 0; g < 4; ++g) o[g] = (f32x4){0.f, 0.f, 0.f, 0.f};
  float m_run[4], l_run[4];
#pragma unroll
  for (int r = 0; r < 4; ++r) { m_run[r] = -NEGMAX; l_run[r] = 0.f; }

  // register prefetch of the HBM rel stream (1 iter deep) + cmask
  float rl[4][4], cmv[4];
#pragma unroll
  for (int r = 0; r < 4; ++r)
#pragma unroll
    for (int c = 0; c < 4; ++c)
      rl[r][c] = relg[(size_t)(quad * 4 + r) * 1024 + c * 16 + lanelo];
#pragma unroll
  for (int c = 0; c < 4; ++c) cmv[c] = (cmg[c * 16 + lanelo] != 0) ? 1.f : 0.f;

  for (int kb = 0; kb < 16; ++kb) {
    const int ko = kb * 64;

    // K frags for this iter (L2/L3-resident; issued first, consumed by S)
    short8 kf0[4], kf1[4];
#pragma unroll
    for (int c = 0; c < 4; ++c) {
      const unsigned short* kr = kg + (size_t)(ko + c * 16 + lanelo) * 64 + quad * 8;
      kf0[c] = *(const short8*)(kr);
      kf1[c] = *(const short8*)(kr + 32);
    }
    // V frags for this iter (consumed after softmax — ~500 cyc of cover)
    short8 vf[4][2];
#pragma unroll
    for (int g = 0; g < 4; ++g)
#pragma unroll
      for (int c2 = 0; c2 < 2; ++c2)
        vf[g][c2] = *(const short8*)(vg + (size_t)(g * 16 + lanelo) * 1024 + ko + c2 * 32 + quad * 8);

    // S = Q K^T : 16 q-rows x 64 keys
    f32x4 s[4];
#pragma unroll
    for (int c = 0; c < 4; ++c) {
      s[c] = (f32x4){0.f, 0.f, 0.f, 0.f};
      s[c] = __builtin_amdgcn_mfma_f32_16x16x32_bf16(qf0, kf0[c], s[c], 0, 0, 0);
      s[c] = __builtin_amdgcn_mfma_f32_16x16x32_bf16(qf1, kf1[c], s[c], 0, 0, 0);
    }

    // prefetch next iter's rel/cmask while softmax runs
    float rn[4][4], cn[4];
    if (kb + 1 < 16) {
#pragma unroll
      for (int r = 0; r < 4; ++r)
#pragma unroll
        for (int c = 0; c < 4; ++c)
          rn[r][c] = relg[(size_t)(quad * 4 + r) * 1024 + ko + 64 + c * 16 + lanelo];
#pragma unroll
      for (int c = 0; c < 4; ++c) cn[c] = (cmg[ko + 64 + c * 16 + lanelo] != 0) ? 1.f : 0.f;
    }

    // online softmax (row stats across the 16 lanes of each quad)
#pragma unroll
    for (int r = 0; r < 4; ++r) {
      const bool qok = qmv[r] != 0.f;
      float x[4], mloc = -NEGMAX;
#pragma unroll
      for (int c = 0; c < 4; ++c) {
        x[c] = (qok && cmv[c] != 0.f) ? s[c][r] * SCALE + rl[r][c] : -NEGMAX;
        mloc = fmaxf(mloc, x[c]);
      }
      for (int off = 1; off < 16; off <<= 1) mloc = fmaxf(mloc, __shfl_xor(mloc, off));
      float mnew = fmaxf(m_run[r], mloc);
      float alpha = __expf(m_run[r] - mnew);
      m_run[r] = mnew;
      float ps = 0.f;
      unsigned short pb[4];
#pragma unroll
      for (int c = 0; c < 4; ++c) {
        float p = __expf(x[c] - mnew);
        ps += p;
        pb[c] = f2bf(p);
      }
      for (int off = 1; off < 16; off <<= 1) ps += __shfl_xor(ps, off);
      l_run[r] = l_run[r] * alpha + ps;
#pragma unroll
      for (int g = 0; g < 4; ++g) o[g][r] *= alpha;
#pragma unroll
      for (int c = 0; c < 4; ++c) Pl[(quad * 4 + r) * 72 + c * 16 + lanelo] = pb[c];
    }

    if (kb + 1 < 16) {
#pragma unroll
      for (int r = 0; r < 4; ++r)
#pragma unroll
        for (int c = 0; c < 4; ++c) rl[r][c] = rn[r][c];
#pragma unroll
      for (int c = 0; c < 4; ++c) cmv[c] = cn[c];
    }

    // P (A-layout via same-wave LDS transpose) @ V
#pragma unroll
    for (int c2 = 0; c2 < 2; ++c2) {
      short8 pa = *(const short8*)((const char*)Pl + lanelo * 144 + c2 * 64 + quad * 16);
#pragma unroll
      for (int g = 0; g < 4; ++g)
        o[g] = __builtin_amdgcn_mfma_f32_16x16x32_bf16(pa, vf[g][c2], o[g], 0, 0, 0);
    }
  }

#pragma unroll
  for (int r = 0; r < 4; ++r) {
    float inv = 1.f / l_run[r];
    size_t row = (size_t)(b_ * 1024 + qrow0 + quad * 4 + r) * 1024;
#pragma unroll
    for (int g = 0; g < 4; ++g)
      aout[row + h * 64 + g * 16 + lanelo] = f2bf(o[g][r] * inv);
  }
}

// ---------------- launch ----------------------------------------------------
extern "C" void kernel_launch(void* const* d_in, const int* in_sizes, int n_in,
                              void* d_out, int out_size, void* d_ws, size_t ws_size,
                              hipStream_t stream) {
  const float* x = (const float*)d_in[0];
  const float* rel = (const float*)d_in[1];
  const int* qmask = (const int*)d_in[2];
  const int* cmask = (const int*)d_in[3];
  const float* Wq = (const float*)d_in[4];
  const float* Wkv = (const float*)d_in[5];
  const float* Wo = (const float*)d_in[6];
  const float* bo = (const float*)d_in[7];
  float* out = (float*)d_out;

  char* ws = (char*)d_ws;
  const size_t MB = 1024 * 1024;
  unsigned short* w3t = (unsigned short*)(ws);            // 3072x1024 bf16 (6 MB)
  unsigned short* wot = (unsigned short*)(ws + 6 * MB);   // 1024x1024 bf16 (2 MB)
  unsigned short* xb  = (unsigned short*)(ws + 8 * MB);   // 4096x1024 bf16 (8 MB)
  unsigned short* qws = (unsigned short*)(ws + 16 * MB);  // [bh][n][64] (8 MB)
  unsigned short* kws = (unsigned short*)(ws + 24 * MB);  // 8 MB
  unsigned short* vtws = (unsigned short*)(ws + 32 * MB); // [bh][dh][n] (8 MB)
  unsigned short* aout = xb;  // reuse: x dead after QKV GEMM

  cast_x_k<<<4096, 256, 0, stream>>>(x, xb);
  tcast_k<<<dim3(16, 16), 256, 0, stream>>>(Wq, 1024, w3t);
  tcast_k<<<dim3(32, 16), 256, 0, stream>>>(Wkv, 2048, w3t + (size_t)1024 * 1024);
  tcast_k<<<dim3(16, 16), 256, 0, stream>>>(Wo, 1024, wot);
  gemm_bt_k<0><<<dim3(24, 32), 256, 0, stream>>>(xb, w3t, qws, kws, vtws, nullptr, nullptr);
  attn_k<<<dim3(64, 64), 64, 0, stream>>>(qws, kws, vtws, rel, qmask, cmask, aout);
  gemm_bt_k<1><<<dim3(8, 32), 256, 0, stream>>>(aout, wot, nullptr, nullptr, nullptr, bo, out);
}